// Round 23
// baseline (161.437 us; speedup 1.0000x reference)
//
#include <hip/hip_runtime.h>
#include <math.h>

#define R_NODES 1152
#define DIGITS 10
#define OUT_CH 16
#define IN_CH 8
#define BATCH 256
#define COLS 160            // DIGITS*OUT_CH
#define W_PER_R 1280        // DIGITS*OUT_CH*IN_CH
#define MROW 9216           // R*IN_CH
#define NSPLIT 72           // K-split: 16 r-rows (K=128, 2 chunks) per block
#define RPS 16              // rows per split
#define YB_S 8              // k_s batch blocks (32 b each)
#define UP 88               // bf16 LDS row stride (64 K): 2-way alias = free
#define KB 72               // k_b LDS row stride (64 K bf16): 16B-aligned rows
#define BLOG_N 11520        // R*DIGITS
#define NQF 640             // k_qf blocks (64 elems each)

typedef __attribute__((ext_vector_type(8))) short short8v;
typedef __attribute__((ext_vector_type(4))) float floatx4;

__device__ inline unsigned short f2bf(float x) {
    union { float f; unsigned int i; } v; v.f = x;
    unsigned int r = v.i + 0x7FFFu + ((v.i >> 16) & 1u);   // round-nearest-even
    return (unsigned short)(r >> 16);
}
__device__ inline float bf2f(unsigned short x) {
    union { unsigned int i; float f; } v; v.i = ((unsigned int)x) << 16;
    return v.f;
}

// ---------- s partials via MFMA (exact r20 structure, + ctr zeroing) ----------
__global__ __launch_bounds__(256, 3) void k_s(
    const float* __restrict__ u,      // [B][R][8]
    const float* __restrict__ W,      // [R][10][16][8]
    const float* __restrict__ blog4,  // [4][R][10] partial logits (scale-applied)
    unsigned short* __restrict__ part, // [NSPLIT][B][160] bf16
    float* __restrict__ sqz,          // slot to zero (= &sqbuf[it])
    int* __restrict__ ctrz,           // counter to zero (= &ctr[it])
    int nbuf)
{
    __shared__ unsigned short ulds[32 * UP];    // 5.6 KB  [batch][K-chunk]
    __shared__ unsigned short wlds[COLS * UP];  // 28.2 KB [col][K-chunk]
    __shared__ float cs[RPS * DIGITS];          // 160 logits -> c

    const int split = blockIdx.x;
    const int b0 = blockIdx.y * 32;
    const int t = threadIdx.x;
    const int r0 = split * RPS;

    if (split == 0 && blockIdx.y == 0 && t == 0) { *sqz = 0.f; *ctrz = 0; }

    // ---- 1. logits for rows r0..r0+15 (4 coalesced slot reads)
    if (t < RPS * DIGITS) {
        float a = 0.f;
        if (nbuf) {
            a = blog4[r0 * DIGITS + t]
              + blog4[BLOG_N + r0 * DIGITS + t]
              + blog4[2 * BLOG_N + r0 * DIGITS + t]
              + blog4[3 * BLOG_N + r0 * DIGITS + t];
        }
        cs[t] = a;
    }
    __syncthreads();
    if (t < RPS) {
        float e[DIGITS];
        float m = -1e30f;
#pragma unroll
        for (int d = 0; d < DIGITS; ++d) m = fmaxf(m, cs[t*10 + d]);
        float ssum = 0.f;
#pragma unroll
        for (int d = 0; d < DIGITS; ++d) { e[d] = expf(cs[t*10 + d] - m); ssum += e[d]; }
        float inv = 1.f / ssum;
#pragma unroll
        for (int d = 0; d < DIGITS; ++d) cs[t*10 + d] = e[d] * inv;
    }
    __syncthreads();

    // ---- 2. MFMA geometry
    const int w = t >> 6, l = t & 63;
    const int mtile = w & 1;
    const int ncol0 = (w >> 1) * 5;
    const int koff = (l >> 4) * 8;
    const int arow = (mtile * 16 + (l & 15)) * UP;

    floatx4 acc[5];
#pragma unroll
    for (int j = 0; j < 5; ++j) acc[j] = (floatx4){0.f, 0.f, 0.f, 0.f};

    // ---- 3. K-chunk loop (2 chunks of K=64) -> MFMA-accumulate
    for (int ch = 0; ch < 2; ++ch) {
        const int rc = r0 + ch * 8;
        float4 uv[2];
#pragma unroll
        for (int p = 0; p < 2; ++p) {
            int idx = t + p * 256;
            int b = idx >> 4, q = idx & 15;
            uv[p] = *(const float4*)(u + (size_t)(b0 + b) * (R_NODES * IN_CH)
                                       + (size_t)rc * IN_CH + q * 4);
        }
        float4 wr[10];
        {
            const float4* Wg = (const float4*)(W + (size_t)rc * W_PER_R);
#pragma unroll
            for (int p = 0; p < 10; ++p) wr[p] = Wg[t + p * 256];
        }
        if (ch) __syncthreads();
#pragma unroll
        for (int p = 0; p < 2; ++p) {
            int idx = t + p * 256;
            int b = idx >> 4, q = idx & 15;
            *(short4*)&ulds[b * UP + q * 4] =
                make_short4((short)f2bf(uv[p].x), (short)f2bf(uv[p].y),
                            (short)f2bf(uv[p].z), (short)f2bf(uv[p].w));
        }
#pragma unroll
        for (int p = 0; p < 10; ++p) {
            int e4 = t + p * 256;
            int e  = e4 * 4;
            int r_l = e4 / 320;
            int rem = e - r_l * W_PER_R;
            int col = rem >> 3;
            int i0  = e & 7;
            float cv = cs[(ch * 8 + r_l) * 10 + (rem >> 7)];
            float4 w4 = wr[p];
            *(short4*)&wlds[col * UP + r_l * 8 + i0] =
                make_short4((short)f2bf(w4.x * cv), (short)f2bf(w4.y * cv),
                            (short)f2bf(w4.z * cv), (short)f2bf(w4.w * cv));
        }
        __syncthreads();
        short8v a0 = *(const short8v*)&ulds[arow + koff];
        short8v a1 = *(const short8v*)&ulds[arow + 32 + koff];
#pragma unroll
        for (int j = 0; j < 5; ++j) {
            const int bcol = ((ncol0 + j) * 16 + (l & 15)) * UP;
            short8v bb0 = *(const short8v*)&wlds[bcol + koff];
            short8v bb1 = *(const short8v*)&wlds[bcol + 32 + koff];
            acc[j] = __builtin_amdgcn_mfma_f32_16x16x32_bf16(a0, bb0, acc[j], 0, 0, 0);
            acc[j] = __builtin_amdgcn_mfma_f32_16x16x32_bf16(a1, bb1, acc[j], 0, 0, 0);
        }
    }

    // ---- 4. store bf16 partials
    unsigned short* pp = part + (size_t)split * (BATCH * COLS);
    const int gb = b0 + mtile * 16 + (l >> 4) * 4;
#pragma unroll
    for (int j = 0; j < 5; ++j) {
        const int gc = (ncol0 + j) * 16 + (l & 15);
#pragma unroll
        for (int reg = 0; reg < 4; ++reg)
            pp[(size_t)(gb + reg) * COLS + gc] = f2bf(acc[j][reg]);
    }
}

// ---------- reduce bf16 partials -> s ; accumulate sum-sq (it 0/1) ----------
__global__ void k_sq(const unsigned short* __restrict__ part,
                     float* __restrict__ s,
                     float* __restrict__ sq)
{
    const int t = threadIdx.x;
    const int e0 = blockIdx.x * 64;
    const int el = t & 63, q = t >> 6;
    float v = 0.f;
    for (int sp = q; sp < NSPLIT; sp += 4)
        v += bf2f(part[(size_t)sp * (BATCH * COLS) + e0 + el]);
    __shared__ float red[256];
    red[t] = v;
    __syncthreads();
    if (t < 64) {
        float vv = red[t] + red[t + 64] + red[t + 128] + red[t + 192];
        s[e0 + t] = vv;
        float x = vv * vv;
#pragma unroll
        for (int off = 32; off > 0; off >>= 1)
            x += __shfl_down(x, off, 64);
        if (t == 0) atomicAdd(sq, x);
    }
}

// ---------- agreement: blog4[bq][r,d] (+)= scale * sum_{o,i} W * M_bq[do][ri] ----------
__global__ __launch_bounds__(256, 3) void k_b(
    const float* __restrict__ u,     // [B][9216]
    const float* __restrict__ s,     // [B][160]
    const float* __restrict__ W,     // [R][10][16][8]
    const float* __restrict__ sqp,   // &sqbuf[it]
    float* __restrict__ blog4,       // [4][R][10]
    int first)
{
    __shared__ unsigned short uld[64 * KB];   // 9.2 KB [ri][b]
    __shared__ unsigned short sld[16 * KB];   // 2.3 KB [o][b]
    const int t = threadIdx.x;
    const int rig = blockIdx.x;
    const int bq = blockIdx.y;
    const int b0 = bq * 64;

    // stage u-slice transposed (once): uld[c][b] = u[b0+b][rig*64+c]
#pragma unroll
    for (int p = 0; p < 4; ++p) {
        int idx = t + p * 256;       // 0..1023
        int b = idx >> 4, q = idx & 15;
        float4 v = *(const float4*)(u + (size_t)(b0 + b) * MROW + rig * 64 + q * 4);
        uld[(q*4+0)*KB + b] = f2bf(v.x);
        uld[(q*4+1)*KB + b] = f2bf(v.y);
        uld[(q*4+2)*KB + b] = f2bf(v.z);
        uld[(q*4+3)*KB + b] = f2bf(v.w);
    }

    const int w = t >> 6, l = t & 63;
    const float q0 = *sqp;
    const float scale = sqrtf(q0) / (1.f + q0);
    const int r_l = 2 * w + ((l & 15) >> 3);
    const int r = rig * 8 + r_l;
    float* slot = blog4 + (size_t)bq * BLOG_N;

    for (int d = 0; d < DIGITS; ++d) {
        // stage s-slice transposed: sld[o][b] = s[b0+b][d*16+o]
        int sb = t >> 2, sq_ = t & 3;
        float4 v = *(const float4*)(s + (size_t)(b0 + sb) * COLS + d * 16 + sq_ * 4);
        if (d) __syncthreads();    // prev d's MFMA readers done
        sld[(sq_*4+0)*KB + sb] = f2bf(v.x);
        sld[(sq_*4+1)*KB + sb] = f2bf(v.y);
        sld[(sq_*4+2)*KB + sb] = f2bf(v.z);
        sld[(sq_*4+3)*KB + sb] = f2bf(v.w);
        __syncthreads();

        floatx4 acc = {0.f, 0.f, 0.f, 0.f};
#pragma unroll
        for (int ks = 0; ks < 2; ++ks) {
            int koff = ks * 32 + (l >> 4) * 8;
            short8v av = *(const short8v*)&sld[(l & 15) * KB + koff];
            short8v bv = *(const short8v*)&uld[(w * 16 + (l & 15)) * KB + koff];
            acc = __builtin_amdgcn_mfma_f32_16x16x32_bf16(av, bv, acc, 0, 0, 0);
        }

        // in-register contraction with W
        const float* Wp = W + (size_t)r * W_PER_R + d * 128 + (l & 7);
        float p = 0.f;
#pragma unroll
        for (int reg = 0; reg < 4; ++reg) {
            int o = (l >> 4) * 4 + reg;
            p = fmaf(Wp[o * 8], acc[reg], p);
        }
        p += __shfl_xor(p, 1, 64);
        p += __shfl_xor(p, 2, 64);
        p += __shfl_xor(p, 4, 64);
        p += __shfl_xor(p, 16, 64);
        p += __shfl_xor(p, 32, 64);

        if ((l & 55) == 0) {   // l == 0 or 8: one writer per (r, d)
            float prev = first ? 0.f : slot[r * DIGITS + d];
            slot[r * DIGITS + d] = prev + scale * p;
        }
    }
}

// ---------- it2 fused: reduce(part) -> sq -> out = v*scale ----------
// HOMOGENEOUS handoff (r22 lesson: heterogeneous spin starved producers):
// all 640 blocks do identical reduce work, signal, then wait ~0 (skew only).
// Poll throttled with s_sleep -> negligible coherence traffic. 640 blocks
// all co-resident (launch_bounds(256,4) -> 1024 slots): no deadlock.
__global__ __launch_bounds__(256, 4) void k_qf(
    const unsigned short* __restrict__ part,
    float* __restrict__ sq,
    int* __restrict__ ctr,
    float* __restrict__ out)
{
    const int t = threadIdx.x;
    __shared__ float red[256];
    __shared__ float scale_sh;
    const int e0 = blockIdx.x * 64;
    const int el = t & 63, q = t >> 6;
    float v = 0.f;
    for (int sp = q; sp < NSPLIT; sp += 4)
        v += bf2f(part[(size_t)sp * (BATCH * COLS) + e0 + el]);
    red[t] = v;
    __syncthreads();
    float vv = 0.f;
    if (t < 64) {
        vv = red[t] + red[t + 64] + red[t + 128] + red[t + 192];
        float x = vv * vv;
#pragma unroll
        for (int off = 32; off > 0; off >>= 1)
            x += __shfl_down(x, off, 64);
        if (t == 0) atomicAdd(sq, x);
    }
    __syncthreads();
    __threadfence();
    if (t == 0) {
        __hip_atomic_fetch_add(ctr, 1, __ATOMIC_RELEASE, __HIP_MEMORY_SCOPE_AGENT);
        while (__hip_atomic_load(ctr, __ATOMIC_RELAXED, __HIP_MEMORY_SCOPE_AGENT) < NQF)
            __builtin_amdgcn_s_sleep(8);
        (void)__hip_atomic_load(ctr, __ATOMIC_ACQUIRE, __HIP_MEMORY_SCOPE_AGENT);
        float q0 = __hip_atomic_load(sq, __ATOMIC_RELAXED, __HIP_MEMORY_SCOPE_AGENT);
        scale_sh = sqrtf(q0) / (1.f + q0);
    }
    __syncthreads();
    if (t < 64) out[e0 + t] = vv * scale_sh;
}

extern "C" void kernel_launch(void* const* d_in, const int* in_sizes, int n_in,
                              void* d_out, int out_size, void* d_ws, size_t ws_size,
                              hipStream_t stream)
{
    const float* u = (const float*)d_in[0];   // (256, 1152, 8)
    const float* W = (const float*)d_in[1];   // (1, 1152, 10, 16, 8)
    float* out = (float*)d_out;               // (256, 10, 16)
    float* ws = (float*)d_ws;

    float* s     = ws;                         // 40960 floats
    float* sqbuf = ws + 40960;                 // 3 (+pad)
    int*   ctr   = (int*)(ws + 40992);         // 3 counters (+pad)
    float* blog4 = ws + 41024;                 // 4 * 11520
    unsigned short* part = (unsigned short*)(ws + 41024 + 4 * BLOG_N + 64);  // 72*40960 bf16

    for (int it = 0; it < 3; ++it) {
        k_s<<<dim3(NSPLIT, YB_S), dim3(256), 0, stream>>>(u, W, blog4, part,
                                                          sqbuf + it, ctr + it, it);
        if (it < 2) {
            k_sq<<<dim3(BATCH * COLS / 64), dim3(256), 0, stream>>>(part, s, sqbuf + it);
            k_b<<<dim3(144, 4), dim3(256), 0, stream>>>(u, s, W, sqbuf + it,
                                                        blog4, it == 0 ? 1 : 0);
        } else {
            k_qf<<<dim3(NQF), dim3(256), 0, stream>>>(part, sqbuf + 2, ctr + 2, out);
        }
    }
}

// Round 24
// 96.019 us; speedup vs baseline: 1.6813x; 1.6813x over previous
//
#include <hip/hip_runtime.h>
#include <math.h>

#define R_NODES 1152
#define DIGITS 10
#define OUT_CH 16
#define IN_CH 8
#define BATCH 256
#define COLS 160            // DIGITS*OUT_CH
#define W_PER_R 1280        // DIGITS*OUT_CH*IN_CH
#define MROW 9216           // R*IN_CH
#define NSPLIT 72           // K-split: 16 r-rows (K=128, 2 chunks) per block
#define RPS 16              // rows per split
#define YB_S 8              // k_s batch blocks (32 b each)
#define UP 88               // bf16 LDS row stride (64 K): 2-way alias = free
#define KB 72               // k_b LDS row stride (64 K bf16): 16B-aligned rows
#define BLOG_N 11520        // R*DIGITS

typedef __attribute__((ext_vector_type(8))) short short8v;
typedef __attribute__((ext_vector_type(4))) float floatx4;

__device__ inline unsigned short f2bf(float x) {
    union { float f; unsigned int i; } v; v.f = x;
    unsigned int r = v.i + 0x7FFFu + ((v.i >> 16) & 1u);   // round-nearest-even
    return (unsigned short)(r >> 16);
}
__device__ inline float bf2f(unsigned short x) {
    union { unsigned int i; float f; } v; v.i = ((unsigned int)x) << 16;
    return v.f;
}

// ---------- s partials via MFMA (r20 structure — session best 95.9us) ----------
// r22/r23 lesson: cross-block spin handoff costs 50-90us on the 8-XCD fabric;
// plain kernel boundaries (~3us) win. 9 dispatches = dependency minimum.
__global__ __launch_bounds__(256, 3) void k_s(
    const float* __restrict__ u,      // [B][R][8]
    const float* __restrict__ W,      // [R][10][16][8]
    const float* __restrict__ blog4,  // [4][R][10] partial logits (scale-applied)
    unsigned short* __restrict__ part, // [NSPLIT][B][160] bf16
    float* __restrict__ sqz,          // slot to zero (= &sqbuf[it])
    int nbuf)
{
    __shared__ unsigned short ulds[32 * UP];    // 5.6 KB  [batch][K-chunk]
    __shared__ unsigned short wlds[COLS * UP];  // 28.2 KB [col][K-chunk]
    __shared__ float cs[RPS * DIGITS];          // 160 logits -> c

    const int split = blockIdx.x;
    const int b0 = blockIdx.y * 32;
    const int t = threadIdx.x;
    const int r0 = split * RPS;

    if (split == 0 && blockIdx.y == 0 && t == 0) *sqz = 0.f;

    // ---- 1. logits for rows r0..r0+15 (4 coalesced slot reads)
    if (t < RPS * DIGITS) {
        float a = 0.f;
        if (nbuf) {
            a = blog4[r0 * DIGITS + t]
              + blog4[BLOG_N + r0 * DIGITS + t]
              + blog4[2 * BLOG_N + r0 * DIGITS + t]
              + blog4[3 * BLOG_N + r0 * DIGITS + t];
        }
        cs[t] = a;
    }
    __syncthreads();
    if (t < RPS) {
        float e[DIGITS];
        float m = -1e30f;
#pragma unroll
        for (int d = 0; d < DIGITS; ++d) m = fmaxf(m, cs[t*10 + d]);
        float ssum = 0.f;
#pragma unroll
        for (int d = 0; d < DIGITS; ++d) { e[d] = expf(cs[t*10 + d] - m); ssum += e[d]; }
        float inv = 1.f / ssum;
#pragma unroll
        for (int d = 0; d < DIGITS; ++d) cs[t*10 + d] = e[d] * inv;
    }
    __syncthreads();

    // ---- 2. MFMA geometry
    const int w = t >> 6, l = t & 63;
    const int mtile = w & 1;
    const int ncol0 = (w >> 1) * 5;
    const int koff = (l >> 4) * 8;
    const int arow = (mtile * 16 + (l & 15)) * UP;

    floatx4 acc[5];
#pragma unroll
    for (int j = 0; j < 5; ++j) acc[j] = (floatx4){0.f, 0.f, 0.f, 0.f};

    // ---- 3. K-chunk loop (2 chunks of K=64) -> MFMA-accumulate
    for (int ch = 0; ch < 2; ++ch) {
        const int rc = r0 + ch * 8;
        float4 uv[2];
#pragma unroll
        for (int p = 0; p < 2; ++p) {
            int idx = t + p * 256;
            int b = idx >> 4, q = idx & 15;
            uv[p] = *(const float4*)(u + (size_t)(b0 + b) * (R_NODES * IN_CH)
                                       + (size_t)rc * IN_CH + q * 4);
        }
        float4 wr[10];
        {
            const float4* Wg = (const float4*)(W + (size_t)rc * W_PER_R);
#pragma unroll
            for (int p = 0; p < 10; ++p) wr[p] = Wg[t + p * 256];
        }
        if (ch) __syncthreads();
#pragma unroll
        for (int p = 0; p < 2; ++p) {
            int idx = t + p * 256;
            int b = idx >> 4, q = idx & 15;
            *(short4*)&ulds[b * UP + q * 4] =
                make_short4((short)f2bf(uv[p].x), (short)f2bf(uv[p].y),
                            (short)f2bf(uv[p].z), (short)f2bf(uv[p].w));
        }
#pragma unroll
        for (int p = 0; p < 10; ++p) {
            int e4 = t + p * 256;
            int e  = e4 * 4;
            int r_l = e4 / 320;
            int rem = e - r_l * W_PER_R;
            int col = rem >> 3;
            int i0  = e & 7;
            float cv = cs[(ch * 8 + r_l) * 10 + (rem >> 7)];
            float4 w4 = wr[p];
            *(short4*)&wlds[col * UP + r_l * 8 + i0] =
                make_short4((short)f2bf(w4.x * cv), (short)f2bf(w4.y * cv),
                            (short)f2bf(w4.z * cv), (short)f2bf(w4.w * cv));
        }
        __syncthreads();
        short8v a0 = *(const short8v*)&ulds[arow + koff];
        short8v a1 = *(const short8v*)&ulds[arow + 32 + koff];
#pragma unroll
        for (int j = 0; j < 5; ++j) {
            const int bcol = ((ncol0 + j) * 16 + (l & 15)) * UP;
            short8v bb0 = *(const short8v*)&wlds[bcol + koff];
            short8v bb1 = *(const short8v*)&wlds[bcol + 32 + koff];
            acc[j] = __builtin_amdgcn_mfma_f32_16x16x32_bf16(a0, bb0, acc[j], 0, 0, 0);
            acc[j] = __builtin_amdgcn_mfma_f32_16x16x32_bf16(a1, bb1, acc[j], 0, 0, 0);
        }
    }

    // ---- 4. store bf16 partials
    unsigned short* pp = part + (size_t)split * (BATCH * COLS);
    const int gb = b0 + mtile * 16 + (l >> 4) * 4;
#pragma unroll
    for (int j = 0; j < 5; ++j) {
        const int gc = (ncol0 + j) * 16 + (l & 15);
#pragma unroll
        for (int reg = 0; reg < 4; ++reg)
            pp[(size_t)(gb + reg) * COLS + gc] = f2bf(acc[j][reg]);
    }
}

// ---------- reduce bf16 partials -> s ; accumulate sum-sq into sqbuf[it] ----------
__global__ void k_sq(const unsigned short* __restrict__ part,
                     float* __restrict__ s,
                     float* __restrict__ sq)
{
    const int t = threadIdx.x;
    const int e0 = blockIdx.x * 64;
    const int el = t & 63, q = t >> 6;
    float v = 0.f;
    for (int sp = q; sp < NSPLIT; sp += 4)
        v += bf2f(part[(size_t)sp * (BATCH * COLS) + e0 + el]);
    __shared__ float red[256];
    red[t] = v;
    __syncthreads();
    if (t < 64) {
        float vv = red[t] + red[t + 64] + red[t + 128] + red[t + 192];
        s[e0 + t] = vv;
        float x = vv * vv;
#pragma unroll
        for (int off = 32; off > 0; off >>= 1)
            x += __shfl_down(x, off, 64);
        if (t == 0) atomicAdd(sq, x);
    }
}

// ---------- agreement: blog4[bq][r,d] (+)= scale * sum_{o,i} W * M_bq[do][ri] ----------
__global__ __launch_bounds__(256, 3) void k_b(
    const float* __restrict__ u,     // [B][9216]
    const float* __restrict__ s,     // [B][160]
    const float* __restrict__ W,     // [R][10][16][8]
    const float* __restrict__ sqp,   // &sqbuf[it]
    float* __restrict__ blog4,       // [4][R][10]
    int first)
{
    __shared__ unsigned short uld[64 * KB];   // 9.2 KB [ri][b]
    __shared__ unsigned short sld[16 * KB];   // 2.3 KB [o][b]
    const int t = threadIdx.x;
    const int rig = blockIdx.x;
    const int bq = blockIdx.y;
    const int b0 = bq * 64;

    // stage u-slice transposed (once): uld[c][b] = u[b0+b][rig*64+c]
#pragma unroll
    for (int p = 0; p < 4; ++p) {
        int idx = t + p * 256;       // 0..1023
        int b = idx >> 4, q = idx & 15;
        float4 v = *(const float4*)(u + (size_t)(b0 + b) * MROW + rig * 64 + q * 4);
        uld[(q*4+0)*KB + b] = f2bf(v.x);
        uld[(q*4+1)*KB + b] = f2bf(v.y);
        uld[(q*4+2)*KB + b] = f2bf(v.z);
        uld[(q*4+3)*KB + b] = f2bf(v.w);
    }

    const int w = t >> 6, l = t & 63;
    const float q0 = *sqp;
    const float scale = sqrtf(q0) / (1.f + q0);
    const int r_l = 2 * w + ((l & 15) >> 3);
    const int r = rig * 8 + r_l;
    float* slot = blog4 + (size_t)bq * BLOG_N;

    for (int d = 0; d < DIGITS; ++d) {
        // stage s-slice transposed: sld[o][b] = s[b0+b][d*16+o]
        int sb = t >> 2, sq_ = t & 3;
        float4 v = *(const float4*)(s + (size_t)(b0 + sb) * COLS + d * 16 + sq_ * 4);
        if (d) __syncthreads();    // prev d's MFMA readers done
        sld[(sq_*4+0)*KB + sb] = f2bf(v.x);
        sld[(sq_*4+1)*KB + sb] = f2bf(v.y);
        sld[(sq_*4+2)*KB + sb] = f2bf(v.z);
        sld[(sq_*4+3)*KB + sb] = f2bf(v.w);
        __syncthreads();

        floatx4 acc = {0.f, 0.f, 0.f, 0.f};
#pragma unroll
        for (int ks = 0; ks < 2; ++ks) {
            int koff = ks * 32 + (l >> 4) * 8;
            short8v av = *(const short8v*)&sld[(l & 15) * KB + koff];
            short8v bv = *(const short8v*)&uld[(w * 16 + (l & 15)) * KB + koff];
            acc = __builtin_amdgcn_mfma_f32_16x16x32_bf16(av, bv, acc, 0, 0, 0);
        }

        // in-register contraction with W
        const float* Wp = W + (size_t)r * W_PER_R + d * 128 + (l & 7);
        float p = 0.f;
#pragma unroll
        for (int reg = 0; reg < 4; ++reg) {
            int o = (l >> 4) * 4 + reg;
            p = fmaf(Wp[o * 8], acc[reg], p);
        }
        p += __shfl_xor(p, 1, 64);
        p += __shfl_xor(p, 2, 64);
        p += __shfl_xor(p, 4, 64);
        p += __shfl_xor(p, 16, 64);
        p += __shfl_xor(p, 32, 64);

        if ((l & 55) == 0) {   // l == 0 or 8: one writer per (r, d)
            float prev = first ? 0.f : slot[r * DIGITS + d];
            slot[r * DIGITS + d] = prev + scale * p;
        }
    }
}

// ---------- final output: v = s * sqrt(sq)/(1+sq) ----------
__global__ void k_scale(const float* __restrict__ s,
                        const float* __restrict__ sq,
                        float* __restrict__ out)
{
    int e = blockIdx.x * 256 + threadIdx.x;
    float q = *sq;
    float scale = sqrtf(q) / (1.f + q);
    out[e] = s[e] * scale;
}

extern "C" void kernel_launch(void* const* d_in, const int* in_sizes, int n_in,
                              void* d_out, int out_size, void* d_ws, size_t ws_size,
                              hipStream_t stream)
{
    const float* u = (const float*)d_in[0];   // (256, 1152, 8)
    const float* W = (const float*)d_in[1];   // (1, 1152, 10, 16, 8)
    float* out = (float*)d_out;               // (256, 10, 16)
    float* ws = (float*)d_ws;

    float* s     = ws;                         // 40960 floats
    float* sqbuf = ws + 40960;                 // 3 (+pad to 64)
    float* blog4 = ws + 41024;                 // 4 * 11520
    unsigned short* part = (unsigned short*)(ws + 41024 + 4 * BLOG_N + 64);  // 72*40960 bf16

    for (int it = 0; it < 3; ++it) {
        k_s<<<dim3(NSPLIT, YB_S), dim3(256), 0, stream>>>(u, W, blog4, part,
                                                          sqbuf + it, it);
        k_sq<<<dim3(BATCH * COLS / 64), dim3(256), 0, stream>>>(part, s, sqbuf + it);
        if (it < 2)
            k_b<<<dim3(144, 4), dim3(256), 0, stream>>>(u, s, W, sqbuf + it,
                                                        blog4, it == 0 ? 1 : 0);
        else
            k_scale<<<dim3(BATCH * COLS / 256), dim3(256), 0, stream>>>(s, sqbuf + 2, out);
    }
}